// Round 10
// baseline (753.039 us; speedup 1.0000x reference)
//
#include <hip/hip_runtime.h>

#define NN 50000
#define EE 800000
#define ET 850000   // EE + NN self loops
#define HH 4
#define CC 64
#define FDIM 256    // HH*CC

#define SCAN_BLK 512
#define SCAN_NB ((NN + SCAN_BLK - 1) / SCAN_BLK)   // 98

typedef unsigned short ushort;
typedef __bf16 bf16x8 __attribute__((ext_vector_type(8)));
typedef float floatx4 __attribute__((ext_vector_type(4)));
typedef ushort ushort8v __attribute__((ext_vector_type(8)));
struct ushort4s { ushort x, y, z, w; };

__device__ __forceinline__ ushort f2bf(float f) {
  union { float f; unsigned u; } v; v.f = f;
  unsigned r = v.u + 0x7fffu + ((v.u >> 16) & 1u);  // RNE
  return (ushort)(r >> 16);
}
__device__ __forceinline__ float bf2f(ushort u) {
  return __uint_as_float(((unsigned)u) << 16);
}

// ---------- edge-index dtype handling (int32 vs int64 at runtime) ----------
__device__ __forceinline__ int get_edge(const void* p, int is64, long long idx) {
  if (is64) return (int)((const long long*)p)[idx];
  return ((const int*)p)[idx];
}

__global__ void detect_kernel(const unsigned int* p, int* flag) {
  // int64 with values < 50000 => every odd 32-bit word is 0
  __shared__ unsigned red[256];
  int t = threadIdx.x;
  unsigned o = 0;
  for (int i = 0; i < 4; i++) o |= p[(t * 4 + i) * 2 + 1];
  red[t] = o;
  __syncthreads();
  for (int s = 128; s > 0; s >>= 1) {
    if (t < s) red[t] |= red[t + s];
    __syncthreads();
  }
  if (t == 0) *flag = (red[0] == 0) ? 1 : 0;
}

// ---------- CSR build over dst ----------
__global__ void degree_kernel(const void* eidx, const int* flag, int* deg) {
  int k = blockIdx.x * blockDim.x + threadIdx.x;
  if (k >= ET) return;
  int is64 = *flag;
  int dst = (k < EE) ? get_edge(eidx, is64, (long long)EE + k) : (k - EE);
  atomicAdd(&deg[dst], 1);
}

__global__ __launch_bounds__(SCAN_BLK) void scan1_kernel(const int* __restrict__ deg,
                                                         int* __restrict__ rowptr,
                                                         int* __restrict__ bsum) {
  __shared__ int sm[SCAN_BLK];
  int t = threadIdx.x;
  int i = blockIdx.x * SCAN_BLK + t;
  int v = (i < NN) ? deg[i] : 0;
  sm[t] = v;
  __syncthreads();
#pragma unroll
  for (int o = 1; o < SCAN_BLK; o <<= 1) {
    int u = (t >= o) ? sm[t - o] : 0;
    __syncthreads();
    sm[t] += u;
    __syncthreads();
  }
  if (i < NN) rowptr[i] = sm[t] - v;                 // local exclusive
  if (t == SCAN_BLK - 1) bsum[blockIdx.x] = sm[t];   // block total
}

__global__ __launch_bounds__(128) void scan2_kernel(const int* __restrict__ bsum,
                                                    int* __restrict__ boff,
                                                    int* __restrict__ rowptr) {
  __shared__ int sm[128];
  int t = threadIdx.x;
  int v = (t < SCAN_NB) ? bsum[t] : 0;
  sm[t] = v;
  __syncthreads();
#pragma unroll
  for (int o = 1; o < 128; o <<= 1) {
    int u = (t >= o) ? sm[t - o] : 0;
    __syncthreads();
    sm[t] += u;
    __syncthreads();
  }
  if (t < SCAN_NB) boff[t] = sm[t] - v;  // exclusive block offset
  if (t == 0) rowptr[NN] = ET;
}

__global__ __launch_bounds__(SCAN_BLK) void scan3_kernel(int* __restrict__ rowptr,
                                                         int* __restrict__ cursor,
                                                         const int* __restrict__ boff) {
  int i = blockIdx.x * SCAN_BLK + threadIdx.x;
  if (i >= NN) return;
  int v = rowptr[i] + boff[blockIdx.x];
  rowptr[i] = v;
  cursor[i] = v;
}

__global__ void fill_kernel(const void* eidx, const int* flag, int* cursor, int* csr_src) {
  int k = blockIdx.x * blockDim.x + threadIdx.x;
  if (k >= ET) return;
  int is64 = *flag;
  int src, dst;
  if (k < EE) {
    src = get_edge(eidx, is64, k);
    dst = get_edge(eidx, is64, (long long)EE + k);
  } else {
    src = dst = k - EE;
  }
  int pos = atomicAdd(&cursor[dst], 1);
  csr_src[pos] = src;
}

// all three weight transposes in one dispatch (grid.y selects the matrix)
__global__ void conv_w_kernel(const float* __restrict__ W0, const float* __restrict__ W1,
                              const float* __restrict__ W2,
                              ushort* __restrict__ T0, ushort* __restrict__ T1,
                              ushort* __restrict__ T2) {
  const float* W = (blockIdx.y == 0) ? W0 : (blockIdx.y == 1) ? W1 : W2;
  ushort* Wt = (blockIdx.y == 0) ? T0 : (blockIdx.y == 1) ? T1 : T2;
  int idx = blockIdx.x * 256 + threadIdx.x;  // 65536
  int k = idx >> 8, n = idx & 255;
  Wt[n * 256 + k] = f2bf(W[idx]);  // transpose: Wt[n][k]
}

// ---------- bf16 MFMA GEMM, LDS-free, small wave-tile for occupancy ----------
// C[M,256] = A[M,256] @ B[256,256] (B given transposed).
// Block = 64 rows x 128 cols, 4 waves; wave tile = 32x64 (2x4 16x16 subtiles).
// Grid = 1564 blocks = 6256 waves = 24.4 waves/CU (vs 12.2 at 64x64 tiles) —
// the R9 counters showed Occupancy 15.5% / MfmaUtil 3.7%: latency-starved.
// Every lane's fragment is 16 contiguous bytes of A / Bt -> direct global
// loads (L2-resident), zero barriers, zero LDS.
// Epilogue: wave w covers cols bcol0+(w&1)*64..+64 = exactly one head ->
// plain stores of s,d (each (row,head) written by exactly one wave).
template <int AF32>
__global__ __launch_bounds__(256) void gemm_bf16(const void* __restrict__ Ap,
                                                 const ushort* __restrict__ Bt,
                                                 ushort* __restrict__ C,
                                                 const float* __restrict__ as_,
                                                 const float* __restrict__ ad_,
                                                 float* __restrict__ s_arr,
                                                 float* __restrict__ d_arr) {
  int tid = threadIdx.x, w = tid >> 6, l = tid & 63;
  int brow0 = blockIdx.x * 64, bcol0 = blockIdx.y * 128;
  int lm = l & 15, lk = (l >> 4) * 8;
  int wm = (w >> 1) * 2, wn = (w & 1) * 4;   // wave: 2 row-subtiles, 4 col-subtiles

  size_t arow[2];
  const ushort* bg[4];
#pragma unroll
  for (int i = 0; i < 2; i++) {
    int r = min(brow0 + (wm + i) * 16 + lm, NN - 1);
    arow[i] = (size_t)r * 256 + lk;
  }
#pragma unroll
  for (int j = 0; j < 4; j++)
    bg[j] = Bt + (size_t)(bcol0 + (wn + j) * 16 + lm) * 256 + lk;

  floatx4 acc[2][4];
#pragma unroll
  for (int i = 0; i < 2; i++)
#pragma unroll
    for (int j = 0; j < 4; j++) acc[i][j] = floatx4{0.f, 0.f, 0.f, 0.f};

#pragma unroll
  for (int k0 = 0; k0 < 256; k0 += 32) {
    bf16x8 af[2], bfr[4];
#pragma unroll
    for (int i = 0; i < 2; i++) {
      if constexpr (AF32) {
        const float* p = (const float*)Ap + arow[i] + k0;
        float4 u = *(const float4*)p, v = *(const float4*)(p + 4);
        ushort8v t = ushort8v{f2bf(u.x), f2bf(u.y), f2bf(u.z), f2bf(u.w),
                              f2bf(v.x), f2bf(v.y), f2bf(v.z), f2bf(v.w)};
        af[i] = *(bf16x8*)&t;
      } else {
        af[i] = *(const bf16x8*)((const ushort*)Ap + arow[i] + k0);
      }
    }
#pragma unroll
    for (int j = 0; j < 4; j++) bfr[j] = *(const bf16x8*)(bg[j] + k0);
#pragma unroll
    for (int i = 0; i < 2; i++)
#pragma unroll
      for (int j = 0; j < 4; j++)
        acc[i][j] = __builtin_amdgcn_mfma_f32_16x16x32_bf16(af[i], bfr[j], acc[i][j], 0, 0, 0);
  }

  int quad = l >> 4;
  // ----- C store -----
#pragma unroll
  for (int i = 0; i < 2; i++) {
    int r0 = brow0 + (wm + i) * 16 + quad * 4;
#pragma unroll
    for (int j = 0; j < 4; j++) {
      int col = bcol0 + (wn + j) * 16 + lm;
#pragma unroll
      for (int r = 0; r < 4; r++) {
        int row = r0 + r;
        if (row < NN) C[(size_t)row * 256 + col] = f2bf(acc[i][j][r]);
      }
    }
  }
  // ----- s/d epilogue: this wave owns head (bcol0>>6)+(w&1) for its rows -----
  float asv[4], adv[4];
#pragma unroll
  for (int j = 0; j < 4; j++) {
    int col = bcol0 + (wn + j) * 16 + lm;
    asv[j] = as_[col];
    adv[j] = ad_[col];
  }
  int head = (bcol0 >> 6) + (w & 1);
#pragma unroll
  for (int i = 0; i < 2; i++) {
#pragma unroll
    for (int r = 0; r < 4; r++) {
      float sp = acc[i][0][r] * asv[0] + acc[i][1][r] * asv[1] +
                 acc[i][2][r] * asv[2] + acc[i][3][r] * asv[3];
      float dp = acc[i][0][r] * adv[0] + acc[i][1][r] * adv[1] +
                 acc[i][2][r] * adv[2] + acc[i][3][r] * adv[3];
      sp += __shfl_xor(sp, 1); dp += __shfl_xor(dp, 1);
      sp += __shfl_xor(sp, 2); dp += __shfl_xor(dp, 2);
      sp += __shfl_xor(sp, 4); dp += __shfl_xor(dp, 4);
      sp += __shfl_xor(sp, 8); dp += __shfl_xor(dp, 8);
      if (lm == 0) {
        int row = brow0 + (wm + i) * 16 + quad * 4 + r;
        if (row < NN) {
          s_arr[row * HH + head] = sp;   // plain store: unique (row,head) per wave
          d_arr[row * HH + head] = dp;
        }
      }
    }
  }
}

// ---------- aggregation: one wave per node, all heads; fused edge softmax ----------
template <bool CONCAT>
__global__ __launch_bounds__(256) void agg_kernel(const ushort* __restrict__ hb,
                                                  const float* __restrict__ s_arr,
                                                  const float* __restrict__ d_arr,
                                                  const int* __restrict__ rowptr,
                                                  const int* __restrict__ csr_src,
                                                  const float* __restrict__ bias,
                                                  void* __restrict__ outp) {
  int w = __builtin_amdgcn_readfirstlane(threadIdx.x >> 6);
  int l = threadIdx.x & 63;
  int head = l >> 4;
  int n = blockIdx.x * 4 + w;
  int beg = rowptr[n], end = rowptr[n + 1];
  float dh = d_arr[n * HH + head];  // wave-uniform row, per-lane head select
  float a0 = 0.f, a1 = 0.f, a2 = 0.f, a3 = 0.f, den = 0.f;

  int i = beg;
  for (; i + 4 <= end; i += 4) {
    int s0 = csr_src[i], s1 = csr_src[i + 1], s2 = csr_src[i + 2], s3 = csr_src[i + 3];
    float e0 = s_arr[s0 * HH + head] + dh;
    float e1 = s_arr[s1 * HH + head] + dh;
    float e2 = s_arr[s2 * HH + head] + dh;
    float e3 = s_arr[s3 * HH + head] + dh;
    ushort4s h0 = *(const ushort4s*)(hb + (unsigned)(s0 * FDIM + l * 4));
    ushort4s h1 = *(const ushort4s*)(hb + (unsigned)(s1 * FDIM + l * 4));
    ushort4s h2 = *(const ushort4s*)(hb + (unsigned)(s2 * FDIM + l * 4));
    ushort4s h3 = *(const ushort4s*)(hb + (unsigned)(s3 * FDIM + l * 4));
    e0 = (e0 > 0.f) ? e0 : 0.2f * e0;  float w0 = __expf(e0);
    e1 = (e1 > 0.f) ? e1 : 0.2f * e1;  float w1 = __expf(e1);
    e2 = (e2 > 0.f) ? e2 : 0.2f * e2;  float w2 = __expf(e2);
    e3 = (e3 > 0.f) ? e3 : 0.2f * e3;  float w3 = __expf(e3);
    den += (w0 + w1) + (w2 + w3);
    a0 = fmaf(w0, bf2f(h0.x), a0); a1 = fmaf(w0, bf2f(h0.y), a1);
    a2 = fmaf(w0, bf2f(h0.z), a2); a3 = fmaf(w0, bf2f(h0.w), a3);
    a0 = fmaf(w1, bf2f(h1.x), a0); a1 = fmaf(w1, bf2f(h1.y), a1);
    a2 = fmaf(w1, bf2f(h1.z), a2); a3 = fmaf(w1, bf2f(h1.w), a3);
    a0 = fmaf(w2, bf2f(h2.x), a0); a1 = fmaf(w2, bf2f(h2.y), a1);
    a2 = fmaf(w2, bf2f(h2.z), a2); a3 = fmaf(w2, bf2f(h2.w), a3);
    a0 = fmaf(w3, bf2f(h3.x), a0); a1 = fmaf(w3, bf2f(h3.y), a1);
    a2 = fmaf(w3, bf2f(h3.z), a2); a3 = fmaf(w3, bf2f(h3.w), a3);
  }
  for (; i < end; i++) {
    int s0 = csr_src[i];
    float e0 = s_arr[s0 * HH + head] + dh;
    ushort4s h0 = *(const ushort4s*)(hb + (unsigned)(s0 * FDIM + l * 4));
    e0 = (e0 > 0.f) ? e0 : 0.2f * e0;
    float w0 = __expf(e0);
    den += w0;
    a0 = fmaf(w0, bf2f(h0.x), a0); a1 = fmaf(w0, bf2f(h0.y), a1);
    a2 = fmaf(w0, bf2f(h0.z), a2); a3 = fmaf(w0, bf2f(h0.w), a3);
  }
  float inv = 1.0f / den;  // self loop guarantees den > 0
  float r0 = a0 * inv, r1 = a1 * inv, r2 = a2 * inv, r3 = a3 * inv;

  if (CONCAT) {
    float4 bv = ((const float4*)bias)[l];
    ushort4s o;
    o.x = f2bf(r0 + bv.x); o.y = f2bf(r1 + bv.y);
    o.z = f2bf(r2 + bv.z); o.w = f2bf(r3 + bv.w);
    ((ushort4s*)outp)[(unsigned)(n * 64 + l)] = o;
  } else {
    // mean over heads: sum lanes {m, m+16, m+32, m+48}
    r0 += __shfl_xor(r0, 16); r1 += __shfl_xor(r1, 16);
    r2 += __shfl_xor(r2, 16); r3 += __shfl_xor(r3, 16);
    r0 += __shfl_xor(r0, 32); r1 += __shfl_xor(r1, 32);
    r2 += __shfl_xor(r2, 32); r3 += __shfl_xor(r3, 32);
    if (l < 16) {
      float4 bv = ((const float4*)bias)[l];
      float4 o;
      o.x = 0.25f * r0 + bv.x; o.y = 0.25f * r1 + bv.y;
      o.z = 0.25f * r2 + bv.z; o.w = 0.25f * r3 + bv.w;
      ((float4*)outp)[(unsigned)(n * 16 + l)] = o;
    }
  }
}

// ---------- GraphNorm ----------
// ushort4 loads (512B/wave/inst), LDS pre-reduction, 512 atomics per block
__global__ __launch_bounds__(256) void norm_reduce_bf(const ushort* __restrict__ xin,
                                                      float* colsum, float* colsumsq) {
  __shared__ float4 sm1[256], sm2[256];
  int t = threadIdx.x;
  int c4 = (t & 63) * 4;
  int rl = t >> 6;
  int r0 = blockIdx.x * 128;
  int r1 = min(NN, r0 + 128);
  float s0 = 0.f, s1 = 0.f, s2 = 0.f, s3 = 0.f;
  float q0 = 0.f, q1 = 0.f, q2 = 0.f, q3 = 0.f;
  for (int r = r0 + rl; r < r1; r += 4) {
    ushort4s v = *(const ushort4s*)(xin + (size_t)r * FDIM + c4);
    float f0 = bf2f(v.x), f1 = bf2f(v.y), f2 = bf2f(v.z), f3 = bf2f(v.w);
    s0 += f0; q0 += f0 * f0;
    s1 += f1; q1 += f1 * f1;
    s2 += f2; q2 += f2 * f2;
    s3 += f3; q3 += f3 * f3;
  }
  sm1[t] = float4{s0, s1, s2, s3};
  sm2[t] = float4{q0, q1, q2, q3};
  __syncthreads();
  if (t < 64) {
    float4 a = sm1[t], b = sm1[t + 64], c = sm1[t + 128], d = sm1[t + 192];
    atomicAdd(&colsum[c4 + 0], a.x + b.x + c.x + d.x);
    atomicAdd(&colsum[c4 + 1], a.y + b.y + c.y + d.y);
    atomicAdd(&colsum[c4 + 2], a.z + b.z + c.z + d.z);
    atomicAdd(&colsum[c4 + 3], a.w + b.w + c.w + d.w);
    float4 e = sm2[t], f = sm2[t + 64], g = sm2[t + 128], h = sm2[t + 192];
    atomicAdd(&colsumsq[c4 + 0], e.x + f.x + g.x + h.x);
    atomicAdd(&colsumsq[c4 + 1], e.y + f.y + g.y + h.y);
    atomicAdd(&colsumsq[c4 + 2], e.z + f.z + g.z + h.z);
    atomicAdd(&colsumsq[c4 + 3], e.w + f.w + g.w + h.w);
  }
}

__global__ __launch_bounds__(256) void norm_reduce_f32(const float* __restrict__ xin,
                                                       float* colsum, float* colsumsq) {
  int f = threadIdx.x & (CC - 1);
  int rl = threadIdx.x / CC;
  int r0 = blockIdx.x * 128;
  int r1 = min(NN, r0 + 128);
  float s1 = 0.f, s2 = 0.f;
  for (int r = r0 + rl; r < r1; r += 4) {
    float v = xin[(size_t)r * CC + f];
    s1 += v; s2 += v * v;
  }
  atomicAdd(&colsum[f], s1);
  atomicAdd(&colsumsq[f], s2);
}

// finalize folded in: each block recomputes scale/shift, then grid-stride apply
__global__ __launch_bounds__(256) void norm_apply_bf(const ushort* __restrict__ in,
                                                     ushort* __restrict__ outb,
                                                     const float* __restrict__ colsum,
                                                     const float* __restrict__ colsumsq,
                                                     const float* __restrict__ ga,
                                                     const float* __restrict__ gw,
                                                     const float* __restrict__ gb) {
  __shared__ float sc[FDIM], sh[FDIM];
  int t = threadIdx.x;
  {
    const float invn = 1.0f / (float)NN;
    float mu = colsum[t] * invn;
    float ex2 = colsumsq[t] * invn;
    float a = ga[t];
    float var = fmaxf(ex2 - (2.f * a - a * a) * mu * mu, 0.f);
    float s = gw[t] * rsqrtf(var + 1e-5f);
    sc[t] = s; sh[t] = gb[t] - s * a * mu;
  }
  __syncthreads();
  const int total = NN * FDIM / 4;
  for (int i = blockIdx.x * 256 + t; i < total; i += gridDim.x * 256) {
    int f0 = (i * 4) & (FDIM - 1);
    ushort4s v = ((const ushort4s*)in)[i];
    float y0 = sc[f0 + 0] * bf2f(v.x) + sh[f0 + 0];
    float y1 = sc[f0 + 1] * bf2f(v.y) + sh[f0 + 1];
    float y2 = sc[f0 + 2] * bf2f(v.z) + sh[f0 + 2];
    float y3 = sc[f0 + 3] * bf2f(v.w) + sh[f0 + 3];
    ushort4s o;
    o.x = f2bf((y0 > 0.f) ? y0 : 0.01f * y0);
    o.y = f2bf((y1 > 0.f) ? y1 : 0.01f * y1);
    o.z = f2bf((y2 > 0.f) ? y2 : 0.01f * y2);
    o.w = f2bf((y3 > 0.f) ? y3 : 0.01f * y3);
    ((ushort4s*)outb)[i] = o;
  }
}

// ---------- MLP 64->32->16->2 with fused GraphNorm+LeakyReLU on input ----------
__global__ __launch_bounds__(256) void mlp_kernel(const float* __restrict__ xin,
                                                  const float* __restrict__ colsum,
                                                  const float* __restrict__ colsumsq,
                                                  const float* __restrict__ ga,
                                                  const float* __restrict__ gw,
                                                  const float* __restrict__ gb,
                                                  const float* mW0, const float* mb0,
                                                  const float* mW1, const float* mb1,
                                                  const float* mW2, const float* mb2,
                                                  float* __restrict__ out) {
  __shared__ float W0s[64 * 32];
  __shared__ float W1s[32 * 16];
  __shared__ float W2s[16 * 2];
  __shared__ float b0s[32], b1s[16], b2s[2];
  __shared__ float sc[CC], sh[CC];
  int t = threadIdx.x;
  for (int i = t; i < 2048; i += 256) W0s[i] = mW0[i];
  for (int i = t; i < 512; i += 256) W1s[i] = mW1[i];
  if (t < 32) { W2s[t] = mW2[t]; b0s[t] = mb0[t]; }
  if (t < 16) b1s[t] = mb1[t];
  if (t < 2) b2s[t] = mb2[t];
  if (t < CC) {
    const float invn = 1.0f / (float)NN;
    float mu = colsum[t] * invn;
    float ex2 = colsumsq[t] * invn;
    float a = ga[t];
    float var = fmaxf(ex2 - (2.f * a - a * a) * mu * mu, 0.f);
    float s = gw[t] * rsqrtf(var + 1e-5f);
    sc[t] = s; sh[t] = gb[t] - s * a * mu;
  }
  __syncthreads();
  int node = blockIdx.x * 256 + t;
  if (node >= NN) return;
  float in[64];
  const float* xr = xin + (size_t)node * 64;
#pragma unroll
  for (int k = 0; k < 64; k++) {
    float y = sc[k] * xr[k] + sh[k];
    in[k] = (y > 0.f) ? y : 0.01f * y;   // GraphNorm + LeakyReLU(0.01) fused
  }
  float h1[32];
#pragma unroll
  for (int j = 0; j < 32; j++) h1[j] = b0s[j];
#pragma unroll
  for (int k = 0; k < 64; k++) {
    float v = in[k];
#pragma unroll
    for (int j = 0; j < 32; j++) h1[j] += v * W0s[k * 32 + j];
  }
#pragma unroll
  for (int j = 0; j < 32; j++) h1[j] = fmaxf(h1[j], 0.f);
  float h2[16];
#pragma unroll
  for (int j = 0; j < 16; j++) h2[j] = b1s[j];
#pragma unroll
  for (int k = 0; k < 32; k++) {
    float v = h1[k];
#pragma unroll
    for (int j = 0; j < 16; j++) h2[j] += v * W1s[k * 16 + j];
  }
#pragma unroll
  for (int j = 0; j < 16; j++) h2[j] = fmaxf(h2[j], 0.f);
  float o0 = b2s[0], o1 = b2s[1];
#pragma unroll
  for (int k = 0; k < 16; k++) {
    o0 += h2[k] * W2s[k * 2 + 0];
    o1 += h2[k] * W2s[k * 2 + 1];
  }
  out[(size_t)node * 2 + 0] = o0;
  out[(size_t)node * 2 + 1] = o1;
}

extern "C" void kernel_launch(void* const* d_in, const int* in_sizes, int n_in,
                              void* d_out, int out_size, void* d_ws, size_t ws_size,
                              hipStream_t stream) {
  const float* x = (const float*)d_in[0];
  const void* ei = d_in[1];
  const float* W[3]   = {(const float*)d_in[2],  (const float*)d_in[9],  (const float*)d_in[16]};
  const float* as_[3] = {(const float*)d_in[3],  (const float*)d_in[10], (const float*)d_in[17]};
  const float* ad_[3] = {(const float*)d_in[4],  (const float*)d_in[11], (const float*)d_in[18]};
  const float* b_[3]  = {(const float*)d_in[5],  (const float*)d_in[12], (const float*)d_in[19]};
  const float* gw[3]  = {(const float*)d_in[6],  (const float*)d_in[13], (const float*)d_in[20]};
  const float* gb[3]  = {(const float*)d_in[7],  (const float*)d_in[14], (const float*)d_in[21]};
  const float* ga[3]  = {(const float*)d_in[8],  (const float*)d_in[15], (const float*)d_in[22]};
  const float* mW0 = (const float*)d_in[23];
  const float* mb0 = (const float*)d_in[24];
  const float* mW1 = (const float*)d_in[25];
  const float* mb1 = (const float*)d_in[26];
  const float* mW2 = (const float*)d_in[27];
  const float* mb2 = (const float*)d_in[28];
  float* out = (float*)d_out;

  char* ws = (char*)d_ws;
  size_t off = 0;
  auto take = [&](size_t bytes) -> char* {
    char* p = ws + off;
    off = (off + bytes + 255) & ~(size_t)255;
    return p;
  };
  ushort* hb    = (ushort*)take((size_t)NN * FDIM * 2);
  ushort* yb    = (ushort*)take((size_t)NN * FDIM * 2);
  ushort* aggb  = (ushort*)take((size_t)NN * FDIM * 2);
  float* bufD   = (float*)take((size_t)NN * CC * 4);
  ushort* Wt[3];
  for (int i = 0; i < 3; i++) Wt[i] = (ushort*)take((size_t)256 * 256 * 2);
  float* s_arr  = (float*)take((size_t)NN * HH * 4);
  float* d_arr  = (float*)take((size_t)NN * HH * 4);
  float* colsum   = (float*)take(1024);   // colsum+colsumsq contiguous: one memset
  float* colsumsq = (float*)take(1024);
  int* deg      = (int*)take((size_t)NN * 4);
  int* cursor   = (int*)take((size_t)NN * 4);
  int* rowptr   = (int*)take((size_t)(NN + 1) * 4);
  int* csr_src  = (int*)take((size_t)ET * 4);
  int* bsum     = (int*)take(512);
  int* boff     = (int*)take(512);
  int* flag     = (int*)take(256);

  // CSR build (reused by all 3 layers)
  hipMemsetAsync(deg, 0, (size_t)NN * 4, stream);
  detect_kernel<<<1, 256, 0, stream>>>((const unsigned int*)ei, flag);
  degree_kernel<<<(ET + 255) / 256, 256, 0, stream>>>(ei, flag, deg);
  scan1_kernel<<<SCAN_NB, SCAN_BLK, 0, stream>>>(deg, rowptr, bsum);
  scan2_kernel<<<1, 128, 0, stream>>>(bsum, boff, rowptr);
  scan3_kernel<<<SCAN_NB, SCAN_BLK, 0, stream>>>(rowptr, cursor, boff);
  fill_kernel<<<(ET + 255) / 256, 256, 0, stream>>>(ei, flag, cursor, csr_src);

  // weight prep (x is consumed in f32 directly by layer-0 gemm)
  conv_w_kernel<<<dim3(256, 3), 256, 0, stream>>>(W[0], W[1], W[2], Wt[0], Wt[1], Wt[2]);

  const void* lin = (const void*)x;
  for (int L = 0; L < 3; L++) {
    if (L == 0)
      gemm_bf16<1><<<dim3((NN + 63) / 64, 2), 256, 0, stream>>>(lin, Wt[L], hb,
                                                                as_[L], ad_[L], s_arr, d_arr);
    else
      gemm_bf16<0><<<dim3((NN + 63) / 64, 2), 256, 0, stream>>>(lin, Wt[L], hb,
                                                                as_[L], ad_[L], s_arr, d_arr);
    hipMemsetAsync(colsum, 0, 2048, stream);
    if (L < 2) {
      agg_kernel<true><<<NN / 4, 256, 0, stream>>>(hb, s_arr, d_arr, rowptr, csr_src, b_[L], aggb);
      norm_reduce_bf<<<(NN + 127) / 128, 256, 0, stream>>>(aggb, colsum, colsumsq);
      norm_apply_bf<<<1024, 256, 0, stream>>>(aggb, yb, colsum, colsumsq, ga[L], gw[L], gb[L]);
      lin = (const void*)yb;
    } else {
      agg_kernel<false><<<NN / 4, 256, 0, stream>>>(hb, s_arr, d_arr, rowptr, csr_src, b_[L], bufD);
      norm_reduce_f32<<<(NN + 127) / 128, 256, 0, stream>>>(bufD, colsum, colsumsq);
    }
  }
  mlp_kernel<<<(NN + 255) / 256, 256, 0, stream>>>(bufD, colsum, colsumsq,
                                                   ga[2], gw[2], gb[2],
                                                   mW0, mb0, mW1, mb1, mW2, mb2, out);
}

// Round 11
// 703.233 us; speedup vs baseline: 1.0708x; 1.0708x over previous
//
#include <hip/hip_runtime.h>

#define NN 50000
#define EE 800000
#define ET 850000   // EE + NN self loops
#define HH 4
#define CC 64
#define FDIM 256    // HH*CC

#define SCAN_BLK 512
#define SCAN_NB ((NN + SCAN_BLK - 1) / SCAN_BLK)   // 98

typedef unsigned short ushort;
typedef __bf16 bf16x8 __attribute__((ext_vector_type(8)));
typedef float floatx4 __attribute__((ext_vector_type(4)));
typedef ushort ushort8v __attribute__((ext_vector_type(8)));
struct ushort4s { ushort x, y, z, w; };

__device__ __forceinline__ ushort f2bf(float f) {
  union { float f; unsigned u; } v; v.f = f;
  unsigned r = v.u + 0x7fffu + ((v.u >> 16) & 1u);  // RNE
  return (ushort)(r >> 16);
}
__device__ __forceinline__ float bf2f(ushort u) {
  return __uint_as_float(((unsigned)u) << 16);
}

// ---------- edge-index dtype handling (int32 vs int64 at runtime) ----------
__device__ __forceinline__ int get_edge(const void* p, int is64, long long idx) {
  if (is64) return (int)((const long long*)p)[idx];
  return ((const int*)p)[idx];
}

__global__ void detect_kernel(const unsigned int* p, int* flag) {
  // int64 with values < 50000 => every odd 32-bit word is 0
  __shared__ unsigned red[256];
  int t = threadIdx.x;
  unsigned o = 0;
  for (int i = 0; i < 4; i++) o |= p[(t * 4 + i) * 2 + 1];
  red[t] = o;
  __syncthreads();
  for (int s = 128; s > 0; s >>= 1) {
    if (t < s) red[t] |= red[t + s];
    __syncthreads();
  }
  if (t == 0) *flag = (red[0] == 0) ? 1 : 0;
}

// ---------- CSR build over dst ----------
__global__ void degree_kernel(const void* eidx, const int* flag, int* deg) {
  int k = blockIdx.x * blockDim.x + threadIdx.x;
  if (k >= ET) return;
  int is64 = *flag;
  int dst = (k < EE) ? get_edge(eidx, is64, (long long)EE + k) : (k - EE);
  atomicAdd(&deg[dst], 1);
}

__global__ __launch_bounds__(SCAN_BLK) void scan1_kernel(const int* __restrict__ deg,
                                                         int* __restrict__ rowptr,
                                                         int* __restrict__ bsum) {
  __shared__ int sm[SCAN_BLK];
  int t = threadIdx.x;
  int i = blockIdx.x * SCAN_BLK + t;
  int v = (i < NN) ? deg[i] : 0;
  sm[t] = v;
  __syncthreads();
#pragma unroll
  for (int o = 1; o < SCAN_BLK; o <<= 1) {
    int u = (t >= o) ? sm[t - o] : 0;
    __syncthreads();
    sm[t] += u;
    __syncthreads();
  }
  if (i < NN) rowptr[i] = sm[t] - v;                 // local exclusive
  if (t == SCAN_BLK - 1) bsum[blockIdx.x] = sm[t];   // block total
}

__global__ __launch_bounds__(128) void scan2_kernel(const int* __restrict__ bsum,
                                                    int* __restrict__ boff,
                                                    int* __restrict__ rowptr) {
  __shared__ int sm[128];
  int t = threadIdx.x;
  int v = (t < SCAN_NB) ? bsum[t] : 0;
  sm[t] = v;
  __syncthreads();
#pragma unroll
  for (int o = 1; o < 128; o <<= 1) {
    int u = (t >= o) ? sm[t - o] : 0;
    __syncthreads();
    sm[t] += u;
    __syncthreads();
  }
  if (t < SCAN_NB) boff[t] = sm[t] - v;  // exclusive block offset
  if (t == 0) rowptr[NN] = ET;
}

__global__ __launch_bounds__(SCAN_BLK) void scan3_kernel(int* __restrict__ rowptr,
                                                         int* __restrict__ cursor,
                                                         const int* __restrict__ boff) {
  int i = blockIdx.x * SCAN_BLK + threadIdx.x;
  if (i >= NN) return;
  int v = rowptr[i] + boff[blockIdx.x];
  rowptr[i] = v;
  cursor[i] = v;
}

__global__ void fill_kernel(const void* eidx, const int* flag, int* cursor, int* csr_src) {
  int k = blockIdx.x * blockDim.x + threadIdx.x;
  if (k >= ET) return;
  int is64 = *flag;
  int src, dst;
  if (k < EE) {
    src = get_edge(eidx, is64, k);
    dst = get_edge(eidx, is64, (long long)EE + k);
  } else {
    src = dst = k - EE;
  }
  int pos = atomicAdd(&cursor[dst], 1);
  csr_src[pos] = src;
}

// all three weight transposes in one dispatch (grid.y selects the matrix)
__global__ void conv_w_kernel(const float* __restrict__ W0, const float* __restrict__ W1,
                              const float* __restrict__ W2,
                              ushort* __restrict__ T0, ushort* __restrict__ T1,
                              ushort* __restrict__ T2) {
  const float* W = (blockIdx.y == 0) ? W0 : (blockIdx.y == 1) ? W1 : W2;
  ushort* Wt = (blockIdx.y == 0) ? T0 : (blockIdx.y == 1) ? T1 : T2;
  int idx = blockIdx.x * 256 + threadIdx.x;  // 65536
  int k = idx >> 8, n = idx & 255;
  Wt[n * 256 + k] = f2bf(W[idx]);  // transpose: Wt[n][k]
}

// ---------- bf16 MFMA GEMM (R8 LDS structure) + no-atomic s/d epilogue ----------
// MODE 0: A is f32 (layer 0 reads x directly), converted inline.
// MODE 1: A is bf16 aggregation output; GraphNorm+LeakyReLU(0.01) applied
//         inline during staging (sc/sh computed in prologue from colsum/colsumsq
//         of the PREVIOUS layer's reduce) — replaces the norm_apply kernel and
//         the 51 MB yb round-trip. Rounding chain identical to the standalone
//         apply kernel -> bit-identical numerics.
// Epilogue: wave w of block (x,y) holds the COMPLETE head y*2+(w&1) for rows
// brow0+(w>>1)*64..+64 -> plain stores of s,d (each (row,head) written once).
template <int MODE>
__global__ __launch_bounds__(256) void gemm_bf16(const void* __restrict__ Ap,
                                                 const ushort* __restrict__ Bt,
                                                 ushort* __restrict__ C,
                                                 const float* __restrict__ as_,
                                                 const float* __restrict__ ad_,
                                                 float* __restrict__ s_arr,
                                                 float* __restrict__ d_arr,
                                                 const float* __restrict__ colsum,
                                                 const float* __restrict__ colsumsq,
                                                 const float* __restrict__ ga,
                                                 const float* __restrict__ gw,
                                                 const float* __restrict__ gb) {
  __shared__ ushort As[8 * 512];
  __shared__ ushort Bs[8 * 512];
  __shared__ float scs[FDIM], shs[FDIM];
  int tid = threadIdx.x, w = tid >> 6, l = tid & 63;
  int brow0 = blockIdx.x * 128, bcol0 = blockIdx.y * 128;
  int lm = l & 15, lk = (l >> 4) * 8;
  int s0 = 2 * w, s1 = 2 * w + 1;
  int ar0 = min(brow0 + s0 * 16 + lm, NN - 1);
  int ar1 = min(brow0 + s1 * 16 + lm, NN - 1);
  size_t arow0 = (size_t)ar0 * 256 + lk;
  size_t arow1 = (size_t)ar1 * 256 + lk;
  const ushort* bg0 = Bt + (size_t)(bcol0 + s0 * 16 + lm) * 256 + lk;
  const ushort* bg1 = Bt + (size_t)(bcol0 + s1 * 16 + lm) * 256 + lk;

  if constexpr (MODE == 1) {
    // prologue: per-feature scale/shift from previous layer's norm stats
    const float invn = 1.0f / (float)NN;
    float mu = colsum[tid] * invn;
    float ex2 = colsumsq[tid] * invn;
    float a = ga[tid];
    float var = fmaxf(ex2 - (2.f * a - a * a) * mu * mu, 0.f);
    float s = gw[tid] * rsqrtf(var + 1e-5f);
    scs[tid] = s;
    shs[tid] = gb[tid] - s * a * mu;
    __syncthreads();
  }

  floatx4 acc[4][4];
#pragma unroll
  for (int i = 0; i < 4; i++)
#pragma unroll
    for (int j = 0; j < 4; j++) acc[i][j] = floatx4{0.f, 0.f, 0.f, 0.f};

  int wm = (w >> 1) * 4, wn = (w & 1) * 4;

  for (int k0 = 0; k0 < 256; k0 += 32) {
    ushort8v a0, a1;
    if constexpr (MODE == 0) {
      const float* p0 = (const float*)Ap + arow0 + k0;
      const float* p1 = (const float*)Ap + arow1 + k0;
      float4 u0 = *(const float4*)p0, v0 = *(const float4*)(p0 + 4);
      float4 u1 = *(const float4*)p1, v1 = *(const float4*)(p1 + 4);
      a0 = ushort8v{f2bf(u0.x), f2bf(u0.y), f2bf(u0.z), f2bf(u0.w),
                    f2bf(v0.x), f2bf(v0.y), f2bf(v0.z), f2bf(v0.w)};
      a1 = ushort8v{f2bf(u1.x), f2bf(u1.y), f2bf(u1.z), f2bf(u1.w),
                    f2bf(v1.x), f2bf(v1.y), f2bf(v1.z), f2bf(v1.w)};
    } else {
      ushort8v r0 = *(const ushort8v*)((const ushort*)Ap + arow0 + k0);
      ushort8v r1 = *(const ushort8v*)((const ushort*)Ap + arow1 + k0);
      int kb = k0 + lk;
#pragma unroll
      for (int j = 0; j < 8; j++) {
        float sc = scs[kb + j], sh = shs[kb + j];
        float y0 = fmaf(sc, bf2f(r0[j]), sh);
        float y1 = fmaf(sc, bf2f(r1[j]), sh);
        y0 = fmaxf(y0, 0.01f * y0);   // LeakyReLU(0.01)
        y1 = fmaxf(y1, 0.01f * y1);
        a0[j] = f2bf(y0);
        a1[j] = f2bf(y1);
      }
    }
    ushort8v b0 = *(const ushort8v*)(bg0 + k0);
    ushort8v b1 = *(const ushort8v*)(bg1 + k0);
    *(ushort8v*)&As[s0 * 512 + l * 8] = a0;
    *(ushort8v*)&As[s1 * 512 + l * 8] = a1;
    *(ushort8v*)&Bs[s0 * 512 + l * 8] = b0;
    *(ushort8v*)&Bs[s1 * 512 + l * 8] = b1;
    __syncthreads();
    bf16x8 af[4], bfr[4];
#pragma unroll
    for (int i = 0; i < 4; i++) af[i] = *(const bf16x8*)&As[(wm + i) * 512 + l * 8];
#pragma unroll
    for (int j = 0; j < 4; j++) bfr[j] = *(const bf16x8*)&Bs[(wn + j) * 512 + l * 8];
#pragma unroll
    for (int i = 0; i < 4; i++)
#pragma unroll
      for (int j = 0; j < 4; j++)
        acc[i][j] = __builtin_amdgcn_mfma_f32_16x16x32_bf16(af[i], bfr[j], acc[i][j], 0, 0, 0);
    __syncthreads();
  }

  int quad = l >> 4;
  // ----- C store -----
#pragma unroll
  for (int i = 0; i < 4; i++) {
    int r0 = brow0 + (wm + i) * 16 + quad * 4;
#pragma unroll
    for (int j = 0; j < 4; j++) {
      int col = bcol0 + (wn + j) * 16 + lm;
#pragma unroll
      for (int r = 0; r < 4; r++) {
        int row = r0 + r;
        if (row < NN) C[(size_t)row * 256 + col] = f2bf(acc[i][j][r]);
      }
    }
  }
  // ----- s/d epilogue: this wave owns head (bcol0>>6)+(wn>>2) for its rows -----
  float asv[4], adv[4];
#pragma unroll
  for (int j = 0; j < 4; j++) {
    int col = bcol0 + (wn + j) * 16 + lm;
    asv[j] = as_[col];
    adv[j] = ad_[col];
  }
  int head = (bcol0 >> 6) + (wn >> 2);
#pragma unroll
  for (int i = 0; i < 4; i++) {
#pragma unroll
    for (int r = 0; r < 4; r++) {
      float sp = acc[i][0][r] * asv[0] + acc[i][1][r] * asv[1] +
                 acc[i][2][r] * asv[2] + acc[i][3][r] * asv[3];
      float dp = acc[i][0][r] * adv[0] + acc[i][1][r] * adv[1] +
                 acc[i][2][r] * adv[2] + acc[i][3][r] * adv[3];
      sp += __shfl_xor(sp, 1); dp += __shfl_xor(dp, 1);
      sp += __shfl_xor(sp, 2); dp += __shfl_xor(dp, 2);
      sp += __shfl_xor(sp, 4); dp += __shfl_xor(dp, 4);
      sp += __shfl_xor(sp, 8); dp += __shfl_xor(dp, 8);
      if (lm == 0) {
        int row = brow0 + (wm + i) * 16 + quad * 4 + r;
        if (row < NN) {
          s_arr[row * HH + head] = sp;   // plain store: unique (row,head) per wave
          d_arr[row * HH + head] = dp;
        }
      }
    }
  }
}

// ---------- aggregation: one wave per node, all heads; fused edge softmax ----------
template <bool CONCAT>
__global__ __launch_bounds__(256) void agg_kernel(const ushort* __restrict__ hb,
                                                  const float* __restrict__ s_arr,
                                                  const float* __restrict__ d_arr,
                                                  const int* __restrict__ rowptr,
                                                  const int* __restrict__ csr_src,
                                                  const float* __restrict__ bias,
                                                  void* __restrict__ outp) {
  int w = __builtin_amdgcn_readfirstlane(threadIdx.x >> 6);
  int l = threadIdx.x & 63;
  int head = l >> 4;
  int n = blockIdx.x * 4 + w;
  int beg = rowptr[n], end = rowptr[n + 1];
  float dh = d_arr[n * HH + head];  // wave-uniform row, per-lane head select
  float a0 = 0.f, a1 = 0.f, a2 = 0.f, a3 = 0.f, den = 0.f;

  int i = beg;
  for (; i + 4 <= end; i += 4) {
    int s0 = csr_src[i], s1 = csr_src[i + 1], s2 = csr_src[i + 2], s3 = csr_src[i + 3];
    float e0 = s_arr[s0 * HH + head] + dh;
    float e1 = s_arr[s1 * HH + head] + dh;
    float e2 = s_arr[s2 * HH + head] + dh;
    float e3 = s_arr[s3 * HH + head] + dh;
    ushort4s h0 = *(const ushort4s*)(hb + (unsigned)(s0 * FDIM + l * 4));
    ushort4s h1 = *(const ushort4s*)(hb + (unsigned)(s1 * FDIM + l * 4));
    ushort4s h2 = *(const ushort4s*)(hb + (unsigned)(s2 * FDIM + l * 4));
    ushort4s h3 = *(const ushort4s*)(hb + (unsigned)(s3 * FDIM + l * 4));
    e0 = (e0 > 0.f) ? e0 : 0.2f * e0;  float w0 = __expf(e0);
    e1 = (e1 > 0.f) ? e1 : 0.2f * e1;  float w1 = __expf(e1);
    e2 = (e2 > 0.f) ? e2 : 0.2f * e2;  float w2 = __expf(e2);
    e3 = (e3 > 0.f) ? e3 : 0.2f * e3;  float w3 = __expf(e3);
    den += (w0 + w1) + (w2 + w3);
    a0 = fmaf(w0, bf2f(h0.x), a0); a1 = fmaf(w0, bf2f(h0.y), a1);
    a2 = fmaf(w0, bf2f(h0.z), a2); a3 = fmaf(w0, bf2f(h0.w), a3);
    a0 = fmaf(w1, bf2f(h1.x), a0); a1 = fmaf(w1, bf2f(h1.y), a1);
    a2 = fmaf(w1, bf2f(h1.z), a2); a3 = fmaf(w1, bf2f(h1.w), a3);
    a0 = fmaf(w2, bf2f(h2.x), a0); a1 = fmaf(w2, bf2f(h2.y), a1);
    a2 = fmaf(w2, bf2f(h2.z), a2); a3 = fmaf(w2, bf2f(h2.w), a3);
    a0 = fmaf(w3, bf2f(h3.x), a0); a1 = fmaf(w3, bf2f(h3.y), a1);
    a2 = fmaf(w3, bf2f(h3.z), a2); a3 = fmaf(w3, bf2f(h3.w), a3);
  }
  for (; i < end; i++) {
    int s0 = csr_src[i];
    float e0 = s_arr[s0 * HH + head] + dh;
    ushort4s h0 = *(const ushort4s*)(hb + (unsigned)(s0 * FDIM + l * 4));
    e0 = (e0 > 0.f) ? e0 : 0.2f * e0;
    float w0 = __expf(e0);
    den += w0;
    a0 = fmaf(w0, bf2f(h0.x), a0); a1 = fmaf(w0, bf2f(h0.y), a1);
    a2 = fmaf(w0, bf2f(h0.z), a2); a3 = fmaf(w0, bf2f(h0.w), a3);
  }
  float inv = 1.0f / den;  // self loop guarantees den > 0
  float r0 = a0 * inv, r1 = a1 * inv, r2 = a2 * inv, r3 = a3 * inv;

  if (CONCAT) {
    float4 bv = ((const float4*)bias)[l];
    ushort4s o;
    o.x = f2bf(r0 + bv.x); o.y = f2bf(r1 + bv.y);
    o.z = f2bf(r2 + bv.z); o.w = f2bf(r3 + bv.w);
    ((ushort4s*)outp)[(unsigned)(n * 64 + l)] = o;
  } else {
    // mean over heads: sum lanes {m, m+16, m+32, m+48}
    r0 += __shfl_xor(r0, 16); r1 += __shfl_xor(r1, 16);
    r2 += __shfl_xor(r2, 16); r3 += __shfl_xor(r3, 16);
    r0 += __shfl_xor(r0, 32); r1 += __shfl_xor(r1, 32);
    r2 += __shfl_xor(r2, 32); r3 += __shfl_xor(r3, 32);
    if (l < 16) {
      float4 bv = ((const float4*)bias)[l];
      float4 o;
      o.x = 0.25f * r0 + bv.x; o.y = 0.25f * r1 + bv.y;
      o.z = 0.25f * r2 + bv.z; o.w = 0.25f * r3 + bv.w;
      ((float4*)outp)[(unsigned)(n * 16 + l)] = o;
    }
  }
}

// ---------- GraphNorm reduce ----------
// ushort4 loads (512B/wave/inst), LDS pre-reduction, 512 atomics per block
__global__ __launch_bounds__(256) void norm_reduce_bf(const ushort* __restrict__ xin,
                                                      float* colsum, float* colsumsq) {
  __shared__ float4 sm1[256], sm2[256];
  int t = threadIdx.x;
  int c4 = (t & 63) * 4;
  int rl = t >> 6;
  int r0 = blockIdx.x * 128;
  int r1 = min(NN, r0 + 128);
  float s0 = 0.f, s1 = 0.f, s2 = 0.f, s3 = 0.f;
  float q0 = 0.f, q1 = 0.f, q2 = 0.f, q3 = 0.f;
  for (int r = r0 + rl; r < r1; r += 4) {
    ushort4s v = *(const ushort4s*)(xin + (size_t)r * FDIM + c4);
    float f0 = bf2f(v.x), f1 = bf2f(v.y), f2 = bf2f(v.z), f3 = bf2f(v.w);
    s0 += f0; q0 += f0 * f0;
    s1 += f1; q1 += f1 * f1;
    s2 += f2; q2 += f2 * f2;
    s3 += f3; q3 += f3 * f3;
  }
  sm1[t] = float4{s0, s1, s2, s3};
  sm2[t] = float4{q0, q1, q2, q3};
  __syncthreads();
  if (t < 64) {
    float4 a = sm1[t], b = sm1[t + 64], c = sm1[t + 128], d = sm1[t + 192];
    atomicAdd(&colsum[c4 + 0], a.x + b.x + c.x + d.x);
    atomicAdd(&colsum[c4 + 1], a.y + b.y + c.y + d.y);
    atomicAdd(&colsum[c4 + 2], a.z + b.z + c.z + d.z);
    atomicAdd(&colsum[c4 + 3], a.w + b.w + c.w + d.w);
    float4 e = sm2[t], f = sm2[t + 64], g = sm2[t + 128], h = sm2[t + 192];
    atomicAdd(&colsumsq[c4 + 0], e.x + f.x + g.x + h.x);
    atomicAdd(&colsumsq[c4 + 1], e.y + f.y + g.y + h.y);
    atomicAdd(&colsumsq[c4 + 2], e.z + f.z + g.z + h.z);
    atomicAdd(&colsumsq[c4 + 3], e.w + f.w + g.w + h.w);
  }
}

__global__ __launch_bounds__(256) void norm_reduce_f32(const float* __restrict__ xin,
                                                       float* colsum, float* colsumsq) {
  int f = threadIdx.x & (CC - 1);
  int rl = threadIdx.x / CC;
  int r0 = blockIdx.x * 128;
  int r1 = min(NN, r0 + 128);
  float s1 = 0.f, s2 = 0.f;
  for (int r = r0 + rl; r < r1; r += 4) {
    float v = xin[(size_t)r * CC + f];
    s1 += v; s2 += v * v;
  }
  atomicAdd(&colsum[f], s1);
  atomicAdd(&colsumsq[f], s2);
}

// ---------- MLP 64->32->16->2 with fused GraphNorm+LeakyReLU on input ----------
__global__ __launch_bounds__(256) void mlp_kernel(const float* __restrict__ xin,
                                                  const float* __restrict__ colsum,
                                                  const float* __restrict__ colsumsq,
                                                  const float* __restrict__ ga,
                                                  const float* __restrict__ gw,
                                                  const float* __restrict__ gb,
                                                  const float* mW0, const float* mb0,
                                                  const float* mW1, const float* mb1,
                                                  const float* mW2, const float* mb2,
                                                  float* __restrict__ out) {
  __shared__ float W0s[64 * 32];
  __shared__ float W1s[32 * 16];
  __shared__ float W2s[16 * 2];
  __shared__ float b0s[32], b1s[16], b2s[2];
  __shared__ float sc[CC], sh[CC];
  int t = threadIdx.x;
  for (int i = t; i < 2048; i += 256) W0s[i] = mW0[i];
  for (int i = t; i < 512; i += 256) W1s[i] = mW1[i];
  if (t < 32) { W2s[t] = mW2[t]; b0s[t] = mb0[t]; }
  if (t < 16) b1s[t] = mb1[t];
  if (t < 2) b2s[t] = mb2[t];
  if (t < CC) {
    const float invn = 1.0f / (float)NN;
    float mu = colsum[t] * invn;
    float ex2 = colsumsq[t] * invn;
    float a = ga[t];
    float var = fmaxf(ex2 - (2.f * a - a * a) * mu * mu, 0.f);
    float s = gw[t] * rsqrtf(var + 1e-5f);
    sc[t] = s; sh[t] = gb[t] - s * a * mu;
  }
  __syncthreads();
  int node = blockIdx.x * 256 + t;
  if (node >= NN) return;
  float in[64];
  const float* xr = xin + (size_t)node * 64;
#pragma unroll
  for (int k = 0; k < 64; k++) {
    float y = sc[k] * xr[k] + sh[k];
    in[k] = (y > 0.f) ? y : 0.01f * y;   // GraphNorm + LeakyReLU(0.01) fused
  }
  float h1[32];
#pragma unroll
  for (int j = 0; j < 32; j++) h1[j] = b0s[j];
#pragma unroll
  for (int k = 0; k < 64; k++) {
    float v = in[k];
#pragma unroll
    for (int j = 0; j < 32; j++) h1[j] += v * W0s[k * 32 + j];
  }
#pragma unroll
  for (int j = 0; j < 32; j++) h1[j] = fmaxf(h1[j], 0.f);
  float h2[16];
#pragma unroll
  for (int j = 0; j < 16; j++) h2[j] = b1s[j];
#pragma unroll
  for (int k = 0; k < 32; k++) {
    float v = h1[k];
#pragma unroll
    for (int j = 0; j < 16; j++) h2[j] += v * W1s[k * 16 + j];
  }
#pragma unroll
  for (int j = 0; j < 16; j++) h2[j] = fmaxf(h2[j], 0.f);
  float o0 = b2s[0], o1 = b2s[1];
#pragma unroll
  for (int k = 0; k < 16; k++) {
    o0 += h2[k] * W2s[k * 2 + 0];
    o1 += h2[k] * W2s[k * 2 + 1];
  }
  out[(size_t)node * 2 + 0] = o0;
  out[(size_t)node * 2 + 1] = o1;
}

extern "C" void kernel_launch(void* const* d_in, const int* in_sizes, int n_in,
                              void* d_out, int out_size, void* d_ws, size_t ws_size,
                              hipStream_t stream) {
  const float* x = (const float*)d_in[0];
  const void* ei = d_in[1];
  const float* W[3]   = {(const float*)d_in[2],  (const float*)d_in[9],  (const float*)d_in[16]};
  const float* as_[3] = {(const float*)d_in[3],  (const float*)d_in[10], (const float*)d_in[17]};
  const float* ad_[3] = {(const float*)d_in[4],  (const float*)d_in[11], (const float*)d_in[18]};
  const float* b_[3]  = {(const float*)d_in[5],  (const float*)d_in[12], (const float*)d_in[19]};
  const float* gw[3]  = {(const float*)d_in[6],  (const float*)d_in[13], (const float*)d_in[20]};
  const float* gb[3]  = {(const float*)d_in[7],  (const float*)d_in[14], (const float*)d_in[21]};
  const float* ga[3]  = {(const float*)d_in[8],  (const float*)d_in[15], (const float*)d_in[22]};
  const float* mW0 = (const float*)d_in[23];
  const float* mb0 = (const float*)d_in[24];
  const float* mW1 = (const float*)d_in[25];
  const float* mb1 = (const float*)d_in[26];
  const float* mW2 = (const float*)d_in[27];
  const float* mb2 = (const float*)d_in[28];
  float* out = (float*)d_out;

  char* ws = (char*)d_ws;
  size_t off = 0;
  auto take = [&](size_t bytes) -> char* {
    char* p = ws + off;
    off = (off + bytes + 255) & ~(size_t)255;
    return p;
  };
  ushort* hb    = (ushort*)take((size_t)NN * FDIM * 2);
  ushort* aggb  = (ushort*)take((size_t)NN * FDIM * 2);
  float* bufD   = (float*)take((size_t)NN * CC * 4);
  ushort* Wt[3];
  for (int i = 0; i < 3; i++) Wt[i] = (ushort*)take((size_t)256 * 256 * 2);
  float* s_arr  = (float*)take((size_t)NN * HH * 4);
  float* d_arr  = (float*)take((size_t)NN * HH * 4);
  float* colsum   = (float*)take(1024);   // colsum+colsumsq contiguous: one memset
  float* colsumsq = (float*)take(1024);
  int* deg      = (int*)take((size_t)NN * 4);
  int* cursor   = (int*)take((size_t)NN * 4);
  int* rowptr   = (int*)take((size_t)(NN + 1) * 4);
  int* csr_src  = (int*)take((size_t)ET * 4);
  int* bsum     = (int*)take(512);
  int* boff     = (int*)take(512);
  int* flag     = (int*)take(256);

  // CSR build (reused by all 3 layers)
  hipMemsetAsync(deg, 0, (size_t)NN * 4, stream);
  detect_kernel<<<1, 256, 0, stream>>>((const unsigned int*)ei, flag);
  degree_kernel<<<(ET + 255) / 256, 256, 0, stream>>>(ei, flag, deg);
  scan1_kernel<<<SCAN_NB, SCAN_BLK, 0, stream>>>(deg, rowptr, bsum);
  scan2_kernel<<<1, 128, 0, stream>>>(bsum, boff, rowptr);
  scan3_kernel<<<SCAN_NB, SCAN_BLK, 0, stream>>>(rowptr, cursor, boff);
  fill_kernel<<<(ET + 255) / 256, 256, 0, stream>>>(ei, flag, cursor, csr_src);

  // weight prep (x is consumed in f32 directly by layer-0 gemm)
  conv_w_kernel<<<dim3(256, 3), 256, 0, stream>>>(W[0], W[1], W[2], Wt[0], Wt[1], Wt[2]);

  dim3 ggrid((NN + 127) / 128, 2);
  for (int L = 0; L < 3; L++) {
    if (L == 0)
      gemm_bf16<0><<<ggrid, 256, 0, stream>>>((const void*)x, Wt[0], hb,
                                              as_[0], ad_[0], s_arr, d_arr,
                                              nullptr, nullptr, nullptr, nullptr, nullptr);
    else
      // fused GraphNorm(L-1)+LeakyReLU applied to aggb during A-staging
      gemm_bf16<1><<<ggrid, 256, 0, stream>>>((const void*)aggb, Wt[L], hb,
                                              as_[L], ad_[L], s_arr, d_arr,
                                              colsum, colsumsq, ga[L - 1], gw[L - 1], gb[L - 1]);
    hipMemsetAsync(colsum, 0, 2048, stream);  // after gemm consumed prev stats
    if (L < 2) {
      agg_kernel<true><<<NN / 4, 256, 0, stream>>>(hb, s_arr, d_arr, rowptr, csr_src, b_[L], aggb);
      norm_reduce_bf<<<(NN + 127) / 128, 256, 0, stream>>>(aggb, colsum, colsumsq);
    } else {
      agg_kernel<false><<<NN / 4, 256, 0, stream>>>(hb, s_arr, d_arr, rowptr, csr_src, b_[L], bufD);
      norm_reduce_f32<<<(NN + 127) / 128, 256, 0, stream>>>(bufD, colsum, colsumsq);
    }
  }
  mlp_kernel<<<(NN + 255) / 256, 256, 0, stream>>>(bufD, colsum, colsumsq,
                                                   ga[2], gw[2], gb[2],
                                                   mW0, mb0, mW1, mb1, mW2, mb2, out);
}

// Round 12
// 683.440 us; speedup vs baseline: 1.1018x; 1.0290x over previous
//
#include <hip/hip_runtime.h>

#define NN 50000
#define EE 800000
#define ET 850000   // EE + NN self loops
#define HH 4
#define CC 64
#define FDIM 256    // HH*CC

#define SCAN_BLK 512
#define SCAN_NB ((NN + SCAN_BLK - 1) / SCAN_BLK)   // 98

typedef unsigned short ushort;
typedef __bf16 bf16x8 __attribute__((ext_vector_type(8)));
typedef float floatx4 __attribute__((ext_vector_type(4)));
typedef ushort ushort8v __attribute__((ext_vector_type(8)));
struct ushort4s { ushort x, y, z, w; };

__device__ __forceinline__ ushort f2bf(float f) {
  union { float f; unsigned u; } v; v.f = f;
  unsigned r = v.u + 0x7fffu + ((v.u >> 16) & 1u);  // RNE
  return (ushort)(r >> 16);
}
__device__ __forceinline__ float bf2f(ushort u) {
  return __uint_as_float(((unsigned)u) << 16);
}

// ---------- edge-index dtype handling (int32 vs int64 at runtime) ----------
__device__ __forceinline__ int get_edge(const void* p, int is64, long long idx) {
  if (is64) return (int)((const long long*)p)[idx];
  return ((const int*)p)[idx];
}

__global__ void detect_kernel(const unsigned int* p, int* flag) {
  // int64 with values < 50000 => every odd 32-bit word is 0
  __shared__ unsigned red[256];
  int t = threadIdx.x;
  unsigned o = 0;
  for (int i = 0; i < 4; i++) o |= p[(t * 4 + i) * 2 + 1];
  red[t] = o;
  __syncthreads();
  for (int s = 128; s > 0; s >>= 1) {
    if (t < s) red[t] |= red[t + s];
    __syncthreads();
  }
  if (t == 0) *flag = (red[0] == 0) ? 1 : 0;
}

// ---------- CSR build over dst ----------
__global__ void degree_kernel(const void* eidx, const int* flag, int* deg) {
  int k = blockIdx.x * blockDim.x + threadIdx.x;
  if (k >= ET) return;
  int is64 = *flag;
  int dst = (k < EE) ? get_edge(eidx, is64, (long long)EE + k) : (k - EE);
  atomicAdd(&deg[dst], 1);
}

__global__ __launch_bounds__(SCAN_BLK) void scan1_kernel(const int* __restrict__ deg,
                                                         int* __restrict__ rowptr,
                                                         int* __restrict__ bsum) {
  __shared__ int sm[SCAN_BLK];
  int t = threadIdx.x;
  int i = blockIdx.x * SCAN_BLK + t;
  int v = (i < NN) ? deg[i] : 0;
  sm[t] = v;
  __syncthreads();
#pragma unroll
  for (int o = 1; o < SCAN_BLK; o <<= 1) {
    int u = (t >= o) ? sm[t - o] : 0;
    __syncthreads();
    sm[t] += u;
    __syncthreads();
  }
  if (i < NN) rowptr[i] = sm[t] - v;                 // local exclusive
  if (t == SCAN_BLK - 1) bsum[blockIdx.x] = sm[t];   // block total
}

__global__ __launch_bounds__(128) void scan2_kernel(const int* __restrict__ bsum,
                                                    int* __restrict__ boff,
                                                    int* __restrict__ rowptr) {
  __shared__ int sm[128];
  int t = threadIdx.x;
  int v = (t < SCAN_NB) ? bsum[t] : 0;
  sm[t] = v;
  __syncthreads();
#pragma unroll
  for (int o = 1; o < 128; o <<= 1) {
    int u = (t >= o) ? sm[t - o] : 0;
    __syncthreads();
    sm[t] += u;
    __syncthreads();
  }
  if (t < SCAN_NB) boff[t] = sm[t] - v;  // exclusive block offset
  if (t == 0) rowptr[NN] = ET;
}

__global__ __launch_bounds__(SCAN_BLK) void scan3_kernel(int* __restrict__ rowptr,
                                                         int* __restrict__ cursor,
                                                         const int* __restrict__ boff) {
  int i = blockIdx.x * SCAN_BLK + threadIdx.x;
  if (i >= NN) return;
  int v = rowptr[i] + boff[blockIdx.x];
  rowptr[i] = v;
  cursor[i] = v;
}

__global__ void fill_kernel(const void* eidx, const int* flag, int* cursor, int* csr_src) {
  int k = blockIdx.x * blockDim.x + threadIdx.x;
  if (k >= ET) return;
  int is64 = *flag;
  int src, dst;
  if (k < EE) {
    src = get_edge(eidx, is64, k);
    dst = get_edge(eidx, is64, (long long)EE + k);
  } else {
    src = dst = k - EE;
  }
  int pos = atomicAdd(&cursor[dst], 1);
  csr_src[pos] = src;
}

// all three weight transposes in one dispatch (grid.y selects the matrix)
__global__ void conv_w_kernel(const float* __restrict__ W0, const float* __restrict__ W1,
                              const float* __restrict__ W2,
                              ushort* __restrict__ T0, ushort* __restrict__ T1,
                              ushort* __restrict__ T2) {
  const float* W = (blockIdx.y == 0) ? W0 : (blockIdx.y == 1) ? W1 : W2;
  ushort* Wt = (blockIdx.y == 0) ? T0 : (blockIdx.y == 1) ? T1 : T2;
  int idx = blockIdx.x * 256 + threadIdx.x;  // 65536
  int k = idx >> 8, n = idx & 255;
  Wt[n * 256 + k] = f2bf(W[idx]);  // transpose: Wt[n][k]
}

// ---------- bf16 MFMA GEMM: small-tile + LDS (6 blocks/CU) + s/d epilogue ----------
// C[M,256] = A[M,256] @ B[256,256] (B given transposed).
// Block = 64 rows x 128 cols, 4 waves, wave tile 32x64 (2x4 16x16 subtiles).
// 1564 blocks = 6.1 blocks/CU: co-resident blocks' MFMA hides each other's
// barrier drains (R8 LDS @3 blocks/CU had MfmaUtil ~4%; R10 small-tile w/o LDS
// falsified occupancy-alone — this is the untried small-tile+LDS cell).
// LDS 12KB: wave w stages A sub-tile w (16 rows) and B sub-tiles 2w,2w+1.
// MODE 0: A f32 (layer 0), inline cvt. MODE 1: A bf16 agg output, GraphNorm+
// LeakyReLU fused into staging from prev layer's colsum/colsumsq stats.
// Epilogue: wave w covers cols bcol0+(w&1)*64..+64 = one complete head ->
// plain stores of s,d.
template <int MODE>
__global__ __launch_bounds__(256) void gemm_bf16(const void* __restrict__ Ap,
                                                 const ushort* __restrict__ Bt,
                                                 ushort* __restrict__ C,
                                                 const float* __restrict__ as_,
                                                 const float* __restrict__ ad_,
                                                 float* __restrict__ s_arr,
                                                 float* __restrict__ d_arr,
                                                 const float* __restrict__ colsum,
                                                 const float* __restrict__ colsumsq,
                                                 const float* __restrict__ ga,
                                                 const float* __restrict__ gw,
                                                 const float* __restrict__ gb) {
  __shared__ ushort As[4 * 512];
  __shared__ ushort Bs[8 * 512];
  __shared__ float scs[FDIM], shs[FDIM];
  int tid = threadIdx.x, w = tid >> 6, l = tid & 63;
  int brow0 = blockIdx.x * 64, bcol0 = blockIdx.y * 128;
  int lm = l & 15, lk = (l >> 4) * 8;
  // staging addresses: wave w -> A sub-tile w, B sub-tiles 2w, 2w+1
  int arA = min(brow0 + w * 16 + lm, NN - 1);
  size_t arowA = (size_t)arA * 256 + lk;
  const ushort* bg0 = Bt + (size_t)(bcol0 + (2 * w) * 16 + lm) * 256 + lk;
  const ushort* bg1 = Bt + (size_t)(bcol0 + (2 * w + 1) * 16 + lm) * 256 + lk;

  if constexpr (MODE == 1) {
    const float invn = 1.0f / (float)NN;
    float mu = colsum[tid] * invn;
    float ex2 = colsumsq[tid] * invn;
    float a = ga[tid];
    float var = fmaxf(ex2 - (2.f * a - a * a) * mu * mu, 0.f);
    float s = gw[tid] * rsqrtf(var + 1e-5f);
    scs[tid] = s;
    shs[tid] = gb[tid] - s * a * mu;
    __syncthreads();
  }

  floatx4 acc[2][4];
#pragma unroll
  for (int i = 0; i < 2; i++)
#pragma unroll
    for (int j = 0; j < 4; j++) acc[i][j] = floatx4{0.f, 0.f, 0.f, 0.f};

  int wm = (w >> 1) * 2, wn = (w & 1) * 4;   // wave: row sub-tiles wm..wm+1, col sub-tiles wn..wn+3

  for (int k0 = 0; k0 < 256; k0 += 32) {
    ushort8v a0;
    if constexpr (MODE == 0) {
      const float* p0 = (const float*)Ap + arowA + k0;
      float4 u0 = *(const float4*)p0, v0 = *(const float4*)(p0 + 4);
      a0 = ushort8v{f2bf(u0.x), f2bf(u0.y), f2bf(u0.z), f2bf(u0.w),
                    f2bf(v0.x), f2bf(v0.y), f2bf(v0.z), f2bf(v0.w)};
    } else {
      ushort8v r0 = *(const ushort8v*)((const ushort*)Ap + arowA + k0);
      int kb = k0 + lk;
#pragma unroll
      for (int j = 0; j < 8; j++) {
        float sc = scs[kb + j], sh = shs[kb + j];
        float y0 = fmaf(sc, bf2f(r0[j]), sh);
        y0 = fmaxf(y0, 0.01f * y0);   // LeakyReLU(0.01)
        a0[j] = f2bf(y0);
      }
    }
    ushort8v b0 = *(const ushort8v*)(bg0 + k0);
    ushort8v b1 = *(const ushort8v*)(bg1 + k0);
    *(ushort8v*)&As[w * 512 + l * 8] = a0;
    *(ushort8v*)&Bs[(2 * w) * 512 + l * 8] = b0;
    *(ushort8v*)&Bs[(2 * w + 1) * 512 + l * 8] = b1;
    __syncthreads();
    bf16x8 af[2], bfr[4];
#pragma unroll
    for (int i = 0; i < 2; i++) af[i] = *(const bf16x8*)&As[(wm + i) * 512 + l * 8];
#pragma unroll
    for (int j = 0; j < 4; j++) bfr[j] = *(const bf16x8*)&Bs[(wn + j) * 512 + l * 8];
#pragma unroll
    for (int i = 0; i < 2; i++)
#pragma unroll
      for (int j = 0; j < 4; j++)
        acc[i][j] = __builtin_amdgcn_mfma_f32_16x16x32_bf16(af[i], bfr[j], acc[i][j], 0, 0, 0);
    __syncthreads();
  }

  int quad = l >> 4;
  // ----- C store -----
#pragma unroll
  for (int i = 0; i < 2; i++) {
    int r0 = brow0 + (wm + i) * 16 + quad * 4;
#pragma unroll
    for (int j = 0; j < 4; j++) {
      int col = bcol0 + (wn + j) * 16 + lm;
#pragma unroll
      for (int r = 0; r < 4; r++) {
        int row = r0 + r;
        if (row < NN) C[(size_t)row * 256 + col] = f2bf(acc[i][j][r]);
      }
    }
  }
  // ----- s/d epilogue: this wave owns head (bcol0>>6)+(w&1) for its rows -----
  float asv[4], adv[4];
#pragma unroll
  for (int j = 0; j < 4; j++) {
    int col = bcol0 + (wn + j) * 16 + lm;
    asv[j] = as_[col];
    adv[j] = ad_[col];
  }
  int head = (bcol0 >> 6) + (w & 1);
#pragma unroll
  for (int i = 0; i < 2; i++) {
#pragma unroll
    for (int r = 0; r < 4; r++) {
      float sp = acc[i][0][r] * asv[0] + acc[i][1][r] * asv[1] +
                 acc[i][2][r] * asv[2] + acc[i][3][r] * asv[3];
      float dp = acc[i][0][r] * adv[0] + acc[i][1][r] * adv[1] +
                 acc[i][2][r] * adv[2] + acc[i][3][r] * adv[3];
      sp += __shfl_xor(sp, 1); dp += __shfl_xor(dp, 1);
      sp += __shfl_xor(sp, 2); dp += __shfl_xor(dp, 2);
      sp += __shfl_xor(sp, 4); dp += __shfl_xor(dp, 4);
      sp += __shfl_xor(sp, 8); dp += __shfl_xor(dp, 8);
      if (lm == 0) {
        int row = brow0 + (wm + i) * 16 + quad * 4 + r;
        if (row < NN) {
          s_arr[row * HH + head] = sp;   // plain store: unique (row,head) per wave
          d_arr[row * HH + head] = dp;
        }
      }
    }
  }
}

// ---------- aggregation: one wave per node, all heads; fused edge softmax ----------
// unroll 8: more gathers in flight per wave (20 VGPR -> headroom; latency-bound)
template <bool CONCAT>
__global__ __launch_bounds__(256) void agg_kernel(const ushort* __restrict__ hb,
                                                  const float* __restrict__ s_arr,
                                                  const float* __restrict__ d_arr,
                                                  const int* __restrict__ rowptr,
                                                  const int* __restrict__ csr_src,
                                                  const float* __restrict__ bias,
                                                  void* __restrict__ outp) {
  int w = __builtin_amdgcn_readfirstlane(threadIdx.x >> 6);
  int l = threadIdx.x & 63;
  int head = l >> 4;
  int n = blockIdx.x * 4 + w;
  int beg = rowptr[n], end = rowptr[n + 1];
  float dh = d_arr[n * HH + head];
  float a0 = 0.f, a1 = 0.f, a2 = 0.f, a3 = 0.f, den = 0.f;

  int i = beg;
  for (; i + 8 <= end; i += 8) {
    int s0 = csr_src[i], s1 = csr_src[i + 1], s2 = csr_src[i + 2], s3 = csr_src[i + 3];
    int s4 = csr_src[i + 4], s5 = csr_src[i + 5], s6 = csr_src[i + 6], s7 = csr_src[i + 7];
    float e0 = s_arr[s0 * HH + head] + dh;
    float e1 = s_arr[s1 * HH + head] + dh;
    float e2 = s_arr[s2 * HH + head] + dh;
    float e3 = s_arr[s3 * HH + head] + dh;
    float e4 = s_arr[s4 * HH + head] + dh;
    float e5 = s_arr[s5 * HH + head] + dh;
    float e6 = s_arr[s6 * HH + head] + dh;
    float e7 = s_arr[s7 * HH + head] + dh;
    ushort4s h0 = *(const ushort4s*)(hb + (unsigned)(s0 * FDIM + l * 4));
    ushort4s h1 = *(const ushort4s*)(hb + (unsigned)(s1 * FDIM + l * 4));
    ushort4s h2 = *(const ushort4s*)(hb + (unsigned)(s2 * FDIM + l * 4));
    ushort4s h3 = *(const ushort4s*)(hb + (unsigned)(s3 * FDIM + l * 4));
    ushort4s h4 = *(const ushort4s*)(hb + (unsigned)(s4 * FDIM + l * 4));
    ushort4s h5 = *(const ushort4s*)(hb + (unsigned)(s5 * FDIM + l * 4));
    ushort4s h6 = *(const ushort4s*)(hb + (unsigned)(s6 * FDIM + l * 4));
    ushort4s h7 = *(const ushort4s*)(hb + (unsigned)(s7 * FDIM + l * 4));
    e0 = (e0 > 0.f) ? e0 : 0.2f * e0;  float w0 = __expf(e0);
    e1 = (e1 > 0.f) ? e1 : 0.2f * e1;  float w1 = __expf(e1);
    e2 = (e2 > 0.f) ? e2 : 0.2f * e2;  float w2 = __expf(e2);
    e3 = (e3 > 0.f) ? e3 : 0.2f * e3;  float w3 = __expf(e3);
    e4 = (e4 > 0.f) ? e4 : 0.2f * e4;  float w4 = __expf(e4);
    e5 = (e5 > 0.f) ? e5 : 0.2f * e5;  float w5 = __expf(e5);
    e6 = (e6 > 0.f) ? e6 : 0.2f * e6;  float w6 = __expf(e6);
    e7 = (e7 > 0.f) ? e7 : 0.2f * e7;  float w7 = __expf(e7);
    den += ((w0 + w1) + (w2 + w3)) + ((w4 + w5) + (w6 + w7));
    a0 = fmaf(w0, bf2f(h0.x), a0); a1 = fmaf(w0, bf2f(h0.y), a1);
    a2 = fmaf(w0, bf2f(h0.z), a2); a3 = fmaf(w0, bf2f(h0.w), a3);
    a0 = fmaf(w1, bf2f(h1.x), a0); a1 = fmaf(w1, bf2f(h1.y), a1);
    a2 = fmaf(w1, bf2f(h1.z), a2); a3 = fmaf(w1, bf2f(h1.w), a3);
    a0 = fmaf(w2, bf2f(h2.x), a0); a1 = fmaf(w2, bf2f(h2.y), a1);
    a2 = fmaf(w2, bf2f(h2.z), a2); a3 = fmaf(w2, bf2f(h2.w), a3);
    a0 = fmaf(w3, bf2f(h3.x), a0); a1 = fmaf(w3, bf2f(h3.y), a1);
    a2 = fmaf(w3, bf2f(h3.z), a2); a3 = fmaf(w3, bf2f(h3.w), a3);
    a0 = fmaf(w4, bf2f(h4.x), a0); a1 = fmaf(w4, bf2f(h4.y), a1);
    a2 = fmaf(w4, bf2f(h4.z), a2); a3 = fmaf(w4, bf2f(h4.w), a3);
    a0 = fmaf(w5, bf2f(h5.x), a0); a1 = fmaf(w5, bf2f(h5.y), a1);
    a2 = fmaf(w5, bf2f(h5.z), a2); a3 = fmaf(w5, bf2f(h5.w), a3);
    a0 = fmaf(w6, bf2f(h6.x), a0); a1 = fmaf(w6, bf2f(h6.y), a1);
    a2 = fmaf(w6, bf2f(h6.z), a2); a3 = fmaf(w6, bf2f(h6.w), a3);
    a0 = fmaf(w7, bf2f(h7.x), a0); a1 = fmaf(w7, bf2f(h7.y), a1);
    a2 = fmaf(w7, bf2f(h7.z), a2); a3 = fmaf(w7, bf2f(h7.w), a3);
  }
  for (; i + 4 <= end; i += 4) {
    int s0 = csr_src[i], s1 = csr_src[i + 1], s2 = csr_src[i + 2], s3 = csr_src[i + 3];
    float e0 = s_arr[s0 * HH + head] + dh;
    float e1 = s_arr[s1 * HH + head] + dh;
    float e2 = s_arr[s2 * HH + head] + dh;
    float e3 = s_arr[s3 * HH + head] + dh;
    ushort4s h0 = *(const ushort4s*)(hb + (unsigned)(s0 * FDIM + l * 4));
    ushort4s h1 = *(const ushort4s*)(hb + (unsigned)(s1 * FDIM + l * 4));
    ushort4s h2 = *(const ushort4s*)(hb + (unsigned)(s2 * FDIM + l * 4));
    ushort4s h3 = *(const ushort4s*)(hb + (unsigned)(s3 * FDIM + l * 4));
    e0 = (e0 > 0.f) ? e0 : 0.2f * e0;  float w0 = __expf(e0);
    e1 = (e1 > 0.f) ? e1 : 0.2f * e1;  float w1 = __expf(e1);
    e2 = (e2 > 0.f) ? e2 : 0.2f * e2;  float w2 = __expf(e2);
    e3 = (e3 > 0.f) ? e3 : 0.2f * e3;  float w3 = __expf(e3);
    den += (w0 + w1) + (w2 + w3);
    a0 = fmaf(w0, bf2f(h0.x), a0); a1 = fmaf(w0, bf2f(h0.y), a1);
    a2 = fmaf(w0, bf2f(h0.z), a2); a3 = fmaf(w0, bf2f(h0.w), a3);
    a0 = fmaf(w1, bf2f(h1.x), a0); a1 = fmaf(w1, bf2f(h1.y), a1);
    a2 = fmaf(w1, bf2f(h1.z), a2); a3 = fmaf(w1, bf2f(h1.w), a3);
    a0 = fmaf(w2, bf2f(h2.x), a0); a1 = fmaf(w2, bf2f(h2.y), a1);
    a2 = fmaf(w2, bf2f(h2.z), a2); a3 = fmaf(w2, bf2f(h2.w), a3);
    a0 = fmaf(w3, bf2f(h3.x), a0); a1 = fmaf(w3, bf2f(h3.y), a1);
    a2 = fmaf(w3, bf2f(h3.z), a2); a3 = fmaf(w3, bf2f(h3.w), a3);
  }
  for (; i < end; i++) {
    int s0 = csr_src[i];
    float e0 = s_arr[s0 * HH + head] + dh;
    ushort4s h0 = *(const ushort4s*)(hb + (unsigned)(s0 * FDIM + l * 4));
    e0 = (e0 > 0.f) ? e0 : 0.2f * e0;
    float w0 = __expf(e0);
    den += w0;
    a0 = fmaf(w0, bf2f(h0.x), a0); a1 = fmaf(w0, bf2f(h0.y), a1);
    a2 = fmaf(w0, bf2f(h0.z), a2); a3 = fmaf(w0, bf2f(h0.w), a3);
  }
  float inv = 1.0f / den;  // self loop guarantees den > 0
  float r0 = a0 * inv, r1 = a1 * inv, r2 = a2 * inv, r3 = a3 * inv;

  if (CONCAT) {
    float4 bv = ((const float4*)bias)[l];
    ushort4s o;
    o.x = f2bf(r0 + bv.x); o.y = f2bf(r1 + bv.y);
    o.z = f2bf(r2 + bv.z); o.w = f2bf(r3 + bv.w);
    ((ushort4s*)outp)[(unsigned)(n * 64 + l)] = o;
  } else {
    r0 += __shfl_xor(r0, 16); r1 += __shfl_xor(r1, 16);
    r2 += __shfl_xor(r2, 16); r3 += __shfl_xor(r3, 16);
    r0 += __shfl_xor(r0, 32); r1 += __shfl_xor(r1, 32);
    r2 += __shfl_xor(r2, 32); r3 += __shfl_xor(r3, 32);
    if (l < 16) {
      float4 bv = ((const float4*)bias)[l];
      float4 o;
      o.x = 0.25f * r0 + bv.x; o.y = 0.25f * r1 + bv.y;
      o.z = 0.25f * r2 + bv.z; o.w = 0.25f * r3 + bv.w;
      ((float4*)outp)[(unsigned)(n * 16 + l)] = o;
    }
  }
}

// ---------- GraphNorm reduce ----------
__global__ __launch_bounds__(256) void norm_reduce_bf(const ushort* __restrict__ xin,
                                                      float* colsum, float* colsumsq) {
  __shared__ float4 sm1[256], sm2[256];
  int t = threadIdx.x;
  int c4 = (t & 63) * 4;
  int rl = t >> 6;
  int r0 = blockIdx.x * 128;
  int r1 = min(NN, r0 + 128);
  float s0 = 0.f, s1 = 0.f, s2 = 0.f, s3 = 0.f;
  float q0 = 0.f, q1 = 0.f, q2 = 0.f, q3 = 0.f;
  for (int r = r0 + rl; r < r1; r += 4) {
    ushort4s v = *(const ushort4s*)(xin + (size_t)r * FDIM + c4);
    float f0 = bf2f(v.x), f1 = bf2f(v.y), f2 = bf2f(v.z), f3 = bf2f(v.w);
    s0 += f0; q0 += f0 * f0;
    s1 += f1; q1 += f1 * f1;
    s2 += f2; q2 += f2 * f2;
    s3 += f3; q3 += f3 * f3;
  }
  sm1[t] = float4{s0, s1, s2, s3};
  sm2[t] = float4{q0, q1, q2, q3};
  __syncthreads();
  if (t < 64) {
    float4 a = sm1[t], b = sm1[t + 64], c = sm1[t + 128], d = sm1[t + 192];
    atomicAdd(&colsum[c4 + 0], a.x + b.x + c.x + d.x);
    atomicAdd(&colsum[c4 + 1], a.y + b.y + c.y + d.y);
    atomicAdd(&colsum[c4 + 2], a.z + b.z + c.z + d.z);
    atomicAdd(&colsum[c4 + 3], a.w + b.w + c.w + d.w);
    float4 e = sm2[t], f = sm2[t + 64], g = sm2[t + 128], h = sm2[t + 192];
    atomicAdd(&colsumsq[c4 + 0], e.x + f.x + g.x + h.x);
    atomicAdd(&colsumsq[c4 + 1], e.y + f.y + g.y + h.y);
    atomicAdd(&colsumsq[c4 + 2], e.z + f.z + g.z + h.z);
    atomicAdd(&colsumsq[c4 + 3], e.w + f.w + g.w + h.w);
  }
}

__global__ __launch_bounds__(256) void norm_reduce_f32(const float* __restrict__ xin,
                                                       float* colsum, float* colsumsq) {
  int f = threadIdx.x & (CC - 1);
  int rl = threadIdx.x / CC;
  int r0 = blockIdx.x * 128;
  int r1 = min(NN, r0 + 128);
  float s1 = 0.f, s2 = 0.f;
  for (int r = r0 + rl; r < r1; r += 4) {
    float v = xin[(size_t)r * CC + f];
    s1 += v; s2 += v * v;
  }
  atomicAdd(&colsum[f], s1);
  atomicAdd(&colsumsq[f], s2);
}

// ---------- MLP 64->32->16->2 with fused GraphNorm+LeakyReLU on input ----------
__global__ __launch_bounds__(256) void mlp_kernel(const float* __restrict__ xin,
                                                  const float* __restrict__ colsum,
                                                  const float* __restrict__ colsumsq,
                                                  const float* __restrict__ ga,
                                                  const float* __restrict__ gw,
                                                  const float* __restrict__ gb,
                                                  const float* mW0, const float* mb0,
                                                  const float* mW1, const float* mb1,
                                                  const float* mW2, const float* mb2,
                                                  float* __restrict__ out) {
  __shared__ float W0s[64 * 32];
  __shared__ float W1s[32 * 16];
  __shared__ float W2s[16 * 2];
  __shared__ float b0s[32], b1s[16], b2s[2];
  __shared__ float sc[CC], sh[CC];
  int t = threadIdx.x;
  for (int i = t; i < 2048; i += 256) W0s[i] = mW0[i];
  for (int i = t; i < 512; i += 256) W1s[i] = mW1[i];
  if (t < 32) { W2s[t] = mW2[t]; b0s[t] = mb0[t]; }
  if (t < 16) b1s[t] = mb1[t];
  if (t < 2) b2s[t] = mb2[t];
  if (t < CC) {
    const float invn = 1.0f / (float)NN;
    float mu = colsum[t] * invn;
    float ex2 = colsumsq[t] * invn;
    float a = ga[t];
    float var = fmaxf(ex2 - (2.f * a - a * a) * mu * mu, 0.f);
    float s = gw[t] * rsqrtf(var + 1e-5f);
    sc[t] = s; sh[t] = gb[t] - s * a * mu;
  }
  __syncthreads();
  int node = blockIdx.x * 256 + t;
  if (node >= NN) return;
  float in[64];
  const float* xr = xin + (size_t)node * 64;
#pragma unroll
  for (int k = 0; k < 64; k++) {
    float y = sc[k] * xr[k] + sh[k];
    in[k] = (y > 0.f) ? y : 0.01f * y;   // GraphNorm + LeakyReLU(0.01) fused
  }
  float h1[32];
#pragma unroll
  for (int j = 0; j < 32; j++) h1[j] = b0s[j];
#pragma unroll
  for (int k = 0; k < 64; k++) {
    float v = in[k];
#pragma unroll
    for (int j = 0; j < 32; j++) h1[j] += v * W0s[k * 32 + j];
  }
#pragma unroll
  for (int j = 0; j < 32; j++) h1[j] = fmaxf(h1[j], 0.f);
  float h2[16];
#pragma unroll
  for (int j = 0; j < 16; j++) h2[j] = b1s[j];
#pragma unroll
  for (int k = 0; k < 32; k++) {
    float v = h1[k];
#pragma unroll
    for (int j = 0; j < 16; j++) h2[j] += v * W1s[k * 16 + j];
  }
#pragma unroll
  for (int j = 0; j < 16; j++) h2[j] = fmaxf(h2[j], 0.f);
  float o0 = b2s[0], o1 = b2s[1];
#pragma unroll
  for (int k = 0; k < 16; k++) {
    o0 += h2[k] * W2s[k * 2 + 0];
    o1 += h2[k] * W2s[k * 2 + 1];
  }
  out[(size_t)node * 2 + 0] = o0;
  out[(size_t)node * 2 + 1] = o1;
}

extern "C" void kernel_launch(void* const* d_in, const int* in_sizes, int n_in,
                              void* d_out, int out_size, void* d_ws, size_t ws_size,
                              hipStream_t stream) {
  const float* x = (const float*)d_in[0];
  const void* ei = d_in[1];
  const float* W[3]   = {(const float*)d_in[2],  (const float*)d_in[9],  (const float*)d_in[16]};
  const float* as_[3] = {(const float*)d_in[3],  (const float*)d_in[10], (const float*)d_in[17]};
  const float* ad_[3] = {(const float*)d_in[4],  (const float*)d_in[11], (const float*)d_in[18]};
  const float* b_[3]  = {(const float*)d_in[5],  (const float*)d_in[12], (const float*)d_in[19]};
  const float* gw[3]  = {(const float*)d_in[6],  (const float*)d_in[13], (const float*)d_in[20]};
  const float* gb[3]  = {(const float*)d_in[7],  (const float*)d_in[14], (const float*)d_in[21]};
  const float* ga[3]  = {(const float*)d_in[8],  (const float*)d_in[15], (const float*)d_in[22]};
  const float* mW0 = (const float*)d_in[23];
  const float* mb0 = (const float*)d_in[24];
  const float* mW1 = (const float*)d_in[25];
  const float* mb1 = (const float*)d_in[26];
  const float* mW2 = (const float*)d_in[27];
  const float* mb2 = (const float*)d_in[28];
  float* out = (float*)d_out;

  char* ws = (char*)d_ws;
  size_t off = 0;
  auto take = [&](size_t bytes) -> char* {
    char* p = ws + off;
    off = (off + bytes + 255) & ~(size_t)255;
    return p;
  };
  ushort* hb    = (ushort*)take((size_t)NN * FDIM * 2);
  ushort* aggb  = (ushort*)take((size_t)NN * FDIM * 2);
  float* bufD   = (float*)take((size_t)NN * CC * 4);
  ushort* Wt[3];
  for (int i = 0; i < 3; i++) Wt[i] = (ushort*)take((size_t)256 * 256 * 2);
  float* s_arr  = (float*)take((size_t)NN * HH * 4);
  float* d_arr  = (float*)take((size_t)NN * HH * 4);
  // zero-region: deg + 3 per-layer stat buffers (colsum|colsumsq each) -> ONE memset
  char* zbase   = (char*)take(0);
  int* deg      = (int*)take((size_t)NN * 4);
  float* cs[3];
  for (int i = 0; i < 3; i++) cs[i] = (float*)take(2048);   // [0:256)=colsum, [256:512)=colsumsq
  size_t zlen   = (size_t)(((char*)cs[2] + 2048) - zbase);
  int* cursor   = (int*)take((size_t)NN * 4);
  int* rowptr   = (int*)take((size_t)(NN + 1) * 4);
  int* csr_src  = (int*)take((size_t)ET * 4);
  int* bsum     = (int*)take(512);
  int* boff     = (int*)take(512);
  int* flag     = (int*)take(256);

  hipMemsetAsync(zbase, 0, zlen, stream);   // deg + all 3 layers' norm stats

  // CSR build (reused by all 3 layers)
  detect_kernel<<<1, 256, 0, stream>>>((const unsigned int*)ei, flag);
  degree_kernel<<<(ET + 255) / 256, 256, 0, stream>>>(ei, flag, deg);
  scan1_kernel<<<SCAN_NB, SCAN_BLK, 0, stream>>>(deg, rowptr, bsum);
  scan2_kernel<<<1, 128, 0, stream>>>(bsum, boff, rowptr);
  scan3_kernel<<<SCAN_NB, SCAN_BLK, 0, stream>>>(rowptr, cursor, boff);
  fill_kernel<<<(ET + 255) / 256, 256, 0, stream>>>(ei, flag, cursor, csr_src);

  // weight prep (x is consumed in f32 directly by layer-0 gemm)
  conv_w_kernel<<<dim3(256, 3), 256, 0, stream>>>(W[0], W[1], W[2], Wt[0], Wt[1], Wt[2]);

  dim3 ggrid((NN + 63) / 64, 2);
  for (int L = 0; L < 3; L++) {
    if (L == 0)
      gemm_bf16<0><<<ggrid, 256, 0, stream>>>((const void*)x, Wt[0], hb,
                                              as_[0], ad_[0], s_arr, d_arr,
                                              nullptr, nullptr, nullptr, nullptr, nullptr);
    else
      gemm_bf16<1><<<ggrid, 256, 0, stream>>>((const void*)aggb, Wt[L], hb,
                                              as_[L], ad_[L], s_arr, d_arr,
                                              cs[L - 1], cs[L - 1] + 256,
                                              ga[L - 1], gw[L - 1], gb[L - 1]);
    if (L < 2) {
      agg_kernel<true><<<NN / 4, 256, 0, stream>>>(hb, s_arr, d_arr, rowptr, csr_src, b_[L], aggb);
      norm_reduce_bf<<<(NN + 127) / 128, 256, 0, stream>>>(aggb, cs[L], cs[L] + 256);
    } else {
      agg_kernel<false><<<NN / 4, 256, 0, stream>>>(hb, s_arr, d_arr, rowptr, csr_src, b_[L], bufD);
      norm_reduce_f32<<<(NN + 127) / 128, 256, 0, stream>>>(bufD, cs[2], cs[2] + 256);
    }
  }
  mlp_kernel<<<(NN + 255) / 256, 256, 0, stream>>>(bufD, cs[2], cs[2] + 256,
                                                   ga[2], gw[2], gb[2],
                                                   mW0, mb0, mW1, mb1, mW2, mb2, out);
}